// Round 1
// baseline (3226.737 us; speedup 1.0000x reference)
//
#include <hip/hip_runtime.h>

#define NN 100000
#define NE 1600000

// ---------------- degree / normalization ----------------

__global__ __launch_bounds__(256) void k_init_deg(float* deg) {
    int i = blockIdx.x * 256 + threadIdx.x;
    if (i < NN) deg[i] = 1.0f;  // self-loop
}

__global__ __launch_bounds__(256) void k_deg_scatter(const int* __restrict__ dst,
                                                     float* __restrict__ deg) {
    int e = blockIdx.x * 256 + threadIdx.x;
    if (e < NE) atomicAdd(&deg[dst[e]], 1.0f);
}

__global__ __launch_bounds__(256) void k_dinv(float* deg) {
    int i = blockIdx.x * 256 + threadIdx.x;
    if (i < NN) deg[i] = rsqrtf(deg[i]);  // deg >= 1 always
}

// ---------------- MLP GEMMs (fp32 vector) ----------------
// Out[r, c] = act( sum_k A[r,k] * W[k,c] + bias[c] ),  K = 256 fixed.
// 32 rows per block staged in LDS; safe for in-place A==Out.

template<int OC, bool RELU>
__global__ __launch_bounds__(256) void k_gemm(const float* __restrict__ A,
                                              const float* __restrict__ W,
                                              const float* __restrict__ bias,
                                              float* __restrict__ Out) {
    __shared__ float As[32][257];  // +1 pad: rowgroups 8 apart -> distinct banks
    const int t = threadIdx.x;
    const long long row0 = (long long)blockIdx.x * 32;

    // stage 32x256 fp32 rows (coalesced float4)
    {
        const float4* A4 = reinterpret_cast<const float4*>(A + row0 * 256);
        for (int i = t; i < 32 * 64; i += 256) {
            float4 v = A4[i];
            int r = i >> 6, c = (i & 63) << 2;
            As[r][c] = v.x; As[r][c + 1] = v.y; As[r][c + 2] = v.z; As[r][c + 3] = v.w;
        }
    }
    __syncthreads();

    constexpr int CT = OC / 4;    // threads spanning columns
    constexpr int RG = 256 / CT;  // row groups
    constexpr int RP = 32 / RG;   // rows per thread
    const int c0 = (t % CT) * 4;
    const int r0 = (t / CT) * RP;

    float acc[RP][4];
#pragma unroll
    for (int r = 0; r < RP; r++) { acc[r][0] = acc[r][1] = acc[r][2] = acc[r][3] = 0.f; }

    for (int k = 0; k < 256; k++) {
        const float4 w = *reinterpret_cast<const float4*>(W + k * OC + c0);
#pragma unroll
        for (int r = 0; r < RP; r++) {
            float a = As[r0 + r][k];
            acc[r][0] = fmaf(a, w.x, acc[r][0]);
            acc[r][1] = fmaf(a, w.y, acc[r][1]);
            acc[r][2] = fmaf(a, w.z, acc[r][2]);
            acc[r][3] = fmaf(a, w.w, acc[r][3]);
        }
    }

    const float4 b = *reinterpret_cast<const float4*>(bias + c0);
#pragma unroll
    for (int r = 0; r < RP; r++) {
        float4 o;
        o.x = acc[r][0] + b.x; o.y = acc[r][1] + b.y;
        o.z = acc[r][2] + b.z; o.w = acc[r][3] + b.w;
        if (RELU) {
            o.x = fmaxf(o.x, 0.f); o.y = fmaxf(o.y, 0.f);
            o.z = fmaxf(o.z, 0.f); o.w = fmaxf(o.w, 0.f);
        }
        *reinterpret_cast<float4*>(Out + (row0 + r0 + r) * OC + c0) = o;
    }
}

// ---------------- APPNP propagation ----------------

// agg[i][:] = dinv[i]^2 * h[i][:]   (self-loop term; full overwrite)
__global__ __launch_bounds__(256) void k_prop_init(const float* __restrict__ h,
                                                   const float* __restrict__ dinv,
                                                   float* __restrict__ agg) {
    int idx = blockIdx.x * 256 + threadIdx.x;  // over NN*8 float4
    if (idx >= NN * 8) return;
    int i = idx >> 3;
    float d = dinv[i];
    float s = d * d;
    float4 v = reinterpret_cast<const float4*>(h)[idx];
    v.x *= s; v.y *= s; v.z *= s; v.w *= s;
    reinterpret_cast<float4*>(agg)[idx] = v;
}

// agg[dst][:] += dinv[src]*dinv[dst] * h[src][:]   (4 threads per edge, 8 ch each)
__global__ __launch_bounds__(256) void k_scatter(const int* __restrict__ src,
                                                 const int* __restrict__ dst,
                                                 const float* __restrict__ dinv,
                                                 const float* __restrict__ h,
                                                 float* __restrict__ agg) {
    long long tid = (long long)blockIdx.x * 256 + threadIdx.x;
    int e = (int)(tid >> 2);
    if (e >= NE) return;
    int cg = ((int)tid & 3) << 3;
    int s = src[e], d = dst[e];
    float nrm = dinv[s] * dinv[d];
    const float4* hs = reinterpret_cast<const float4*>(h + (long long)s * 32 + cg);
    float4 a = hs[0], b = hs[1];
    float* ad = agg + (long long)d * 32 + cg;
    atomicAdd(ad + 0, nrm * a.x); atomicAdd(ad + 1, nrm * a.y);
    atomicAdd(ad + 2, nrm * a.z); atomicAdd(ad + 3, nrm * a.w);
    atomicAdd(ad + 4, nrm * b.x); atomicAdd(ad + 5, nrm * b.y);
    atomicAdd(ad + 6, nrm * b.z); atomicAdd(ad + 7, nrm * b.w);
}

// out = 0.9*agg + 0.1*h0
__global__ __launch_bounds__(256) void k_combine(const float* __restrict__ agg,
                                                 const float* __restrict__ h0,
                                                 float* __restrict__ out) {
    int idx = blockIdx.x * 256 + threadIdx.x;  // over NN*8 float4
    if (idx >= NN * 8) return;
    float4 a = reinterpret_cast<const float4*>(agg)[idx];
    float4 z = reinterpret_cast<const float4*>(h0)[idx];
    float4 o;
    o.x = 0.9f * a.x + 0.1f * z.x;
    o.y = 0.9f * a.y + 0.1f * z.y;
    o.z = 0.9f * a.z + 0.1f * z.z;
    o.w = 0.9f * a.w + 0.1f * z.w;
    reinterpret_cast<float4*>(out)[idx] = o;
}

// ---------------- launch ----------------

extern "C" void kernel_launch(void* const* d_in, const int* in_sizes, int n_in,
                              void* d_out, int out_size, void* d_ws, size_t ws_size,
                              hipStream_t stream) {
    const float* x     = (const float*)d_in[0];
    const int*   ei    = (const int*)d_in[1];   // [2, NE] int32: row0=src, row1=dst
    const float* W_in  = (const float*)d_in[2];
    const float* b_in  = (const float*)d_in[3];
    const float* W_h   = (const float*)d_in[4];
    const float* b_h   = (const float*)d_in[5];
    const float* W_out = (const float*)d_in[6];
    const float* b_out = (const float*)d_in[7];
    float* out = (float*)d_out;

    const int* srcv = ei;
    const int* dstv = ei + NE;

    char* ws = (char*)d_ws;
    float* h1   = (float*)ws;                               // NN*256
    float* h0   = (float*)(ws + (size_t)NN * 256 * 4);      // NN*32
    float* hb   = h0 + (size_t)NN * 32;                     // NN*32
    float* agg  = hb + (size_t)NN * 32;                     // NN*32
    float* dinv = agg + (size_t)NN * 32;                    // NN

    // degree -> dinv
    k_init_deg<<<(NN + 255) / 256, 256, 0, stream>>>(dinv);
    k_deg_scatter<<<(NE + 255) / 256, 256, 0, stream>>>(dstv, dinv);
    k_dinv<<<(NN + 255) / 256, 256, 0, stream>>>(dinv);

    // MLP
    k_gemm<256, true ><<<NN / 32, 256, 0, stream>>>(x,  W_in,  b_in,  h1);
    k_gemm<256, true ><<<NN / 32, 256, 0, stream>>>(h1, W_h,   b_h,   h1);  // in-place
    k_gemm<32,  false><<<NN / 32, 256, 0, stream>>>(h1, W_out, b_out, h0);

    // APPNP: K = 2
    const float* hin = h0;
    for (int k = 0; k < 2; k++) {
        k_prop_init<<<NN * 8 / 256, 256, 0, stream>>>(hin, dinv, agg);
        k_scatter<<<(NE * 4 + 255) / 256, 256, 0, stream>>>(srcv, dstv, dinv, hin, agg);
        float* hout = (k == 0) ? hb : out;
        k_combine<<<NN * 8 / 256, 256, 0, stream>>>(agg, h0, hout);
        hin = hout;
    }
}

// Round 2
// 796.828 us; speedup vs baseline: 4.0495x; 4.0495x over previous
//
#include <hip/hip_runtime.h>

#define NN 100000
#define NE 1600000

// ---------------- CSR build (dst-sorted edges) ----------------

__global__ __launch_bounds__(256) void k_zero_int(int* p, int n) {
    int i = blockIdx.x * 256 + threadIdx.x;
    if (i < n) p[i] = 0;
}

__global__ __launch_bounds__(256) void k_hist(const int* __restrict__ dst,
                                              int* __restrict__ cnt) {
    int e = blockIdx.x * 256 + threadIdx.x;
    if (e < NE) atomicAdd(&cnt[dst[e]], 1);
}

// exclusive scan, stage 1: per-256 block scan
__global__ __launch_bounds__(256) void k_scan1(const int* __restrict__ cnt,
                                               int* __restrict__ part,
                                               int* __restrict__ bsum, int n) {
    __shared__ int s[256];
    int i = blockIdx.x * 256 + threadIdx.x;
    int v = (i < n) ? cnt[i] : 0;
    s[threadIdx.x] = v;
    __syncthreads();
    for (int off = 1; off < 256; off <<= 1) {
        int t = (threadIdx.x >= off) ? s[threadIdx.x - off] : 0;
        __syncthreads();
        s[threadIdx.x] += t;
        __syncthreads();
    }
    if (i < n) part[i] = s[threadIdx.x] - v;  // exclusive
    if (threadIdx.x == 255) bsum[blockIdx.x] = s[255];
}

// stage 2: single-block exclusive scan of block sums (nb <= 512)
__global__ __launch_bounds__(512) void k_scan2(int* bsum, int nb) {
    __shared__ int s[512];
    int t = threadIdx.x;
    int v = (t < nb) ? bsum[t] : 0;
    s[t] = v;
    __syncthreads();
    for (int off = 1; off < 512; off <<= 1) {
        int u = (t >= off) ? s[t - off] : 0;
        __syncthreads();
        s[t] += u;
        __syncthreads();
    }
    if (t < nb) bsum[t] = s[t] - v;
}

// stage 3: combine, init cursor, compute dinv = rsqrt(deg+1 self-loop)
__global__ __launch_bounds__(256) void k_scan3(const int* __restrict__ part,
                                               const int* __restrict__ bsum,
                                               const int* __restrict__ cnt,
                                               int* __restrict__ row_ptr,
                                               int* __restrict__ cursor,
                                               float* __restrict__ dinv, int n) {
    int i = blockIdx.x * 256 + threadIdx.x;
    if (i < n) {
        int r = part[i] + bsum[blockIdx.x];
        row_ptr[i] = r;
        cursor[i] = r;
        dinv[i] = rsqrtf((float)(cnt[i] + 1));
        if (i == 0) row_ptr[n] = NE;
    }
}

__global__ __launch_bounds__(256) void k_reorder(const int* __restrict__ src,
                                                 const int* __restrict__ dst,
                                                 int* __restrict__ cursor,
                                                 int* __restrict__ col) {
    int e = blockIdx.x * 256 + threadIdx.x;
    if (e < NE) {
        int pos = atomicAdd(&cursor[dst[e]], 1);
        col[pos] = src[e];
    }
}

// ---------------- MLP GEMMs (fp32 vector) ----------------
// Out[r, c] = act( sum_k A[r,k] * W[k,c] + bias[c] ),  K = 256 fixed.
// 32 rows per block staged in LDS; safe for in-place A==Out.

template<int OC, bool RELU>
__global__ __launch_bounds__(256) void k_gemm(const float* __restrict__ A,
                                              const float* __restrict__ W,
                                              const float* __restrict__ bias,
                                              float* __restrict__ Out) {
    __shared__ float As[32][257];
    const int t = threadIdx.x;
    const long long row0 = (long long)blockIdx.x * 32;

    {
        const float4* A4 = reinterpret_cast<const float4*>(A + row0 * 256);
        for (int i = t; i < 32 * 64; i += 256) {
            float4 v = A4[i];
            int r = i >> 6, c = (i & 63) << 2;
            As[r][c] = v.x; As[r][c + 1] = v.y; As[r][c + 2] = v.z; As[r][c + 3] = v.w;
        }
    }
    __syncthreads();

    constexpr int CT = OC / 4;
    constexpr int RG = 256 / CT;
    constexpr int RP = 32 / RG;
    const int c0 = (t % CT) * 4;
    const int r0 = (t / CT) * RP;

    float acc[RP][4];
#pragma unroll
    for (int r = 0; r < RP; r++) { acc[r][0] = acc[r][1] = acc[r][2] = acc[r][3] = 0.f; }

    for (int k = 0; k < 256; k++) {
        const float4 w = *reinterpret_cast<const float4*>(W + k * OC + c0);
#pragma unroll
        for (int r = 0; r < RP; r++) {
            float a = As[r0 + r][k];
            acc[r][0] = fmaf(a, w.x, acc[r][0]);
            acc[r][1] = fmaf(a, w.y, acc[r][1]);
            acc[r][2] = fmaf(a, w.z, acc[r][2]);
            acc[r][3] = fmaf(a, w.w, acc[r][3]);
        }
    }

    const float4 b = *reinterpret_cast<const float4*>(bias + c0);
#pragma unroll
    for (int r = 0; r < RP; r++) {
        float4 o;
        o.x = acc[r][0] + b.x; o.y = acc[r][1] + b.y;
        o.z = acc[r][2] + b.z; o.w = acc[r][3] + b.w;
        if (RELU) {
            o.x = fmaxf(o.x, 0.f); o.y = fmaxf(o.y, 0.f);
            o.z = fmaxf(o.z, 0.f); o.w = fmaxf(o.w, 0.f);
        }
        *reinterpret_cast<float4*>(Out + (row0 + r0 + r) * OC + c0) = o;
    }
}

// ---------------- fused APPNP step (gather, no atomics) ----------------
// One 32-lane half-wave per dst node; lane = channel.
// agg = dinv[d] * ( sum_e dinv[src]*h[src][c]  +  dinv[d]*h[d][c] )
// out = 0.9*agg + 0.1*h0

__global__ __launch_bounds__(256) void k_appnp(const int* __restrict__ row_ptr,
                                               const int* __restrict__ col,
                                               const float* __restrict__ dinv,
                                               const float* __restrict__ h,
                                               const float* __restrict__ h0,
                                               float* __restrict__ out) {
    int node = blockIdx.x * 8 + (threadIdx.x >> 5);
    if (node >= NN) return;
    int c = threadIdx.x & 31;
    int beg = row_ptr[node];
    int end = row_ptr[node + 1];
    float dd = dinv[node];
    float t = dd * h[(size_t)node * 32 + c];  // self-loop (pre dd-scale)
    for (int e = beg; e < end; e++) {
        int s = col[e];
        t = fmaf(dinv[s], h[(size_t)s * 32 + c], t);
    }
    float agg = dd * t;
    out[(size_t)node * 32 + c] = 0.9f * agg + 0.1f * h0[(size_t)node * 32 + c];
}

// ---------------- launch ----------------

extern "C" void kernel_launch(void* const* d_in, const int* in_sizes, int n_in,
                              void* d_out, int out_size, void* d_ws, size_t ws_size,
                              hipStream_t stream) {
    const float* x     = (const float*)d_in[0];
    const int*   ei    = (const int*)d_in[1];   // [2, NE]: row0=src, row1=dst
    const float* W_in  = (const float*)d_in[2];
    const float* b_in  = (const float*)d_in[3];
    const float* W_h   = (const float*)d_in[4];
    const float* b_h   = (const float*)d_in[5];
    const float* W_out = (const float*)d_in[6];
    const float* b_out = (const float*)d_in[7];
    float* out = (float*)d_out;

    const int* srcv = ei;
    const int* dstv = ei + NE;

    char* ws = (char*)d_ws;
    float* h1      = (float*)ws;                            // NN*256 f32
    float* h0      = (float*)(ws + (size_t)NN * 256 * 4);   // NN*32
    float* hb      = h0 + (size_t)NN * 32;                  // NN*32
    float* dinv    = hb + (size_t)NN * 32;                  // NN
    int*   cnt     = (int*)(dinv + NN);                     // NN
    int*   part    = cnt + NN;                              // NN
    int*   row_ptr = part + NN;                             // NN+1
    int*   cursor  = row_ptr + NN + 1;                      // NN
    int*   bsum    = cursor + NN;                           // <=512
    int*   col     = bsum + 512;                            // NE

    const int NB = (NN + 255) / 256;   // 391 scan blocks
    const int EB = (NE + 255) / 256;   // 6250 edge blocks

    // --- CSR build + dinv ---
    k_zero_int<<<NB, 256, 0, stream>>>(cnt, NN);
    k_hist<<<EB, 256, 0, stream>>>(dstv, cnt);
    k_scan1<<<NB, 256, 0, stream>>>(cnt, part, bsum, NN);
    k_scan2<<<1, 512, 0, stream>>>(bsum, NB);
    k_scan3<<<NB, 256, 0, stream>>>(part, bsum, cnt, row_ptr, cursor, dinv, NN);
    k_reorder<<<EB, 256, 0, stream>>>(srcv, dstv, cursor, col);

    // --- MLP ---
    k_gemm<256, true ><<<NN / 32, 256, 0, stream>>>(x,  W_in,  b_in,  h1);
    k_gemm<256, true ><<<NN / 32, 256, 0, stream>>>(h1, W_h,   b_h,   h1);  // in-place
    k_gemm<32,  false><<<NN / 32, 256, 0, stream>>>(h1, W_out, b_out, h0);

    // --- APPNP: K = 2, fused gather + self-loop + combine ---
    k_appnp<<<(NN + 7) / 8, 256, 0, stream>>>(row_ptr, col, dinv, h0, h0, hb);
    k_appnp<<<(NN + 7) / 8, 256, 0, stream>>>(row_ptr, col, dinv, hb, h0, out);
}

// Round 3
// 474.533 us; speedup vs baseline: 6.7998x; 1.6792x over previous
//
#include <hip/hip_runtime.h>

#define NN 100000
#define NE 1600000
#define M_PAD 100032  // 1563 * 64

typedef _Float16 half8v __attribute__((ext_vector_type(8)));
typedef _Float16 half4v __attribute__((ext_vector_type(4)));
typedef float f32x4 __attribute__((ext_vector_type(4)));

// ---------------- CSR build (dst-sorted edges) ----------------

__global__ __launch_bounds__(256) void k_zero_int(int* p, int n) {
    int i = blockIdx.x * 256 + threadIdx.x;
    if (i < n) p[i] = 0;
}

__global__ __launch_bounds__(256) void k_hist(const int* __restrict__ dst,
                                              int* __restrict__ cnt) {
    int e = blockIdx.x * 256 + threadIdx.x;
    if (e < NE) atomicAdd(&cnt[dst[e]], 1);
}

__global__ __launch_bounds__(256) void k_scan1(const int* __restrict__ cnt,
                                               int* __restrict__ part,
                                               int* __restrict__ bsum, int n) {
    __shared__ int s[256];
    int i = blockIdx.x * 256 + threadIdx.x;
    int v = (i < n) ? cnt[i] : 0;
    s[threadIdx.x] = v;
    __syncthreads();
    for (int off = 1; off < 256; off <<= 1) {
        int t = (threadIdx.x >= off) ? s[threadIdx.x - off] : 0;
        __syncthreads();
        s[threadIdx.x] += t;
        __syncthreads();
    }
    if (i < n) part[i] = s[threadIdx.x] - v;
    if (threadIdx.x == 255) bsum[blockIdx.x] = s[255];
}

__global__ __launch_bounds__(512) void k_scan2(int* bsum, int nb) {
    __shared__ int s[512];
    int t = threadIdx.x;
    int v = (t < nb) ? bsum[t] : 0;
    s[t] = v;
    __syncthreads();
    for (int off = 1; off < 512; off <<= 1) {
        int u = (t >= off) ? s[t - off] : 0;
        __syncthreads();
        s[t] += u;
        __syncthreads();
    }
    if (t < nb) bsum[t] = s[t] - v;
}

__global__ __launch_bounds__(256) void k_scan3(const int* __restrict__ part,
                                               const int* __restrict__ bsum,
                                               const int* __restrict__ cnt,
                                               int* __restrict__ row_ptr,
                                               int* __restrict__ cursor,
                                               float* __restrict__ dinv, int n) {
    int i = blockIdx.x * 256 + threadIdx.x;
    if (i < n) {
        int r = part[i] + bsum[blockIdx.x];
        row_ptr[i] = r;
        cursor[i] = r;
        dinv[i] = rsqrtf((float)(cnt[i] + 1));
        if (i == 0) row_ptr[n] = NE;
    }
}

__global__ __launch_bounds__(256) void k_reorder(const int* __restrict__ src,
                                                 const int* __restrict__ dst,
                                                 int* __restrict__ cursor,
                                                 int* __restrict__ col) {
    int e = blockIdx.x * 256 + threadIdx.x;
    if (e < NE) {
        int pos = atomicAdd(&cursor[dst[e]], 1);
        col[pos] = src[e];
    }
}

// ---------------- W -> fp16 B-fragment layout ----------------
// Wf[((kt*(N/16)+nt)*64 + lane)*8 + j] = W[(kt*32 + (lane>>4)*8 + j)*N + nt*16 + (lane&15)]

template<int N>
__global__ __launch_bounds__(256) void k_wfrag(const float* __restrict__ W,
                                               _Float16* __restrict__ Wf) {
    int idx = blockIdx.x * 256 + threadIdx.x;
    if (idx >= 256 * N) return;
    int j = idx & 7;
    int l = (idx >> 3) & 63;
    int f = idx >> 9;
    int nt = f % (N / 16);
    int kt = f / (N / 16);
    int k = kt * 32 + (l >> 4) * 8 + j;
    int c = nt * 16 + (l & 15);
    Wf[idx] = (_Float16)W[k * N + c];
}

// ---------------- MFMA GEMM ----------------
// Out[M_PAD x N] = act(A[. x 256] @ W[256 x N] + bias). 64 rows/block, 4 waves.
// N=256: wave w owns rows[0:64) x cols[w*64, w*64+64)  (WMT=4, WNT=4)
// N=32 : wave w owns rows[w*16,w*16+16) x cols[0:32)   (WMT=1, WNT=2)

template<int N, bool RELU, bool A_FP32, bool OUT_FP16>
__global__ __launch_bounds__(256) void k_gemm_mfma(const void* __restrict__ Ain,
                                                   const _Float16* __restrict__ Wf,
                                                   const float* __restrict__ bias,
                                                   void* __restrict__ Out) {
    __shared__ char lds[64 * 512];  // 64 rows x 256 fp16
    const int t = threadIdx.x;
    const int lane = t & 63;
    const int w = t >> 6;
    const long long row0 = (long long)blockIdx.x * 64;

    // ---- stage A tile into LDS (fp16, XOR-swizzled rows) ----
    if (A_FP32) {
        const float4* A4 = reinterpret_cast<const float4*>((const float*)Ain + row0 * 256);
        for (int i = t; i < 4096; i += 256) {  // 64 rows x 64 float4
            int r = i >> 6, c4 = i & 63;
            float4 v = make_float4(0.f, 0.f, 0.f, 0.f);
            if (row0 + r < NN) v = A4[i];
            half4v hv;
            hv[0] = (_Float16)v.x; hv[1] = (_Float16)v.y;
            hv[2] = (_Float16)v.z; hv[3] = (_Float16)v.w;
            int bo = (r * 512 + c4 * 8) ^ ((r & 7) << 4);
            *reinterpret_cast<half4v*>(lds + bo) = hv;
        }
    } else {
        const half8v* A8 = reinterpret_cast<const half8v*>((const _Float16*)Ain + row0 * 256);
        for (int i = t; i < 2048; i += 256) {  // 64 rows x 32 half8
            int r = i >> 5, c8 = i & 31;
            int bo = (r * 512 + c8 * 16) ^ ((r & 7) << 4);
            *reinterpret_cast<half8v*>(lds + bo) = A8[i];
        }
    }
    __syncthreads();

    constexpr int WMT = (N == 256) ? 4 : 1;
    constexpr int WNT = (N == 256) ? 4 : 2;
    const int rw = (N == 256) ? 0 : w * 16;
    const int cw = (N == 256) ? w * 64 : 0;

    f32x4 acc[WMT][WNT];
#pragma unroll
    for (int mt = 0; mt < WMT; mt++)
#pragma unroll
        for (int nt = 0; nt < WNT; nt++) acc[mt][nt] = (f32x4)0.f;

    const half8v* Wf8 = reinterpret_cast<const half8v*>(Wf);

#pragma unroll
    for (int kt = 0; kt < 8; kt++) {
        half8v a[WMT], b[WNT];
#pragma unroll
        for (int mt = 0; mt < WMT; mt++) {
            int row = rw + mt * 16 + (lane & 15);
            int bo = (row * 512 + kt * 64 + ((lane >> 4) << 4)) ^ ((row & 7) << 4);
            a[mt] = *reinterpret_cast<const half8v*>(lds + bo);
        }
#pragma unroll
        for (int nt = 0; nt < WNT; nt++) {
            int f = kt * (N / 16) + (cw >> 4) + nt;
            b[nt] = Wf8[f * 64 + lane];
        }
#pragma unroll
        for (int mt = 0; mt < WMT; mt++)
#pragma unroll
            for (int nt = 0; nt < WNT; nt++)
                acc[mt][nt] = __builtin_amdgcn_mfma_f32_16x16x32_f16(a[mt], b[nt], acc[mt][nt], 0, 0, 0);
    }

    // ---- epilogue: bias (+relu) + store ----
#pragma unroll
    for (int mt = 0; mt < WMT; mt++)
#pragma unroll
        for (int nt = 0; nt < WNT; nt++) {
            int colc = cw + nt * 16 + (lane & 15);
            float bv = bias[colc];
#pragma unroll
            for (int r = 0; r < 4; r++) {
                long long row = row0 + rw + mt * 16 + (lane >> 4) * 4 + r;
                float v = acc[mt][nt][r] + bv;
                if (RELU) v = fmaxf(v, 0.f);
                if (OUT_FP16) {
                    ((_Float16*)Out)[row * N + colc] = (_Float16)v;
                } else {
                    if (row < NN) ((float*)Out)[row * N + colc] = v;
                }
            }
        }
}

// ---------------- fused APPNP step (gather, no atomics) ----------------

__global__ __launch_bounds__(256) void k_appnp(const int* __restrict__ row_ptr,
                                               const int* __restrict__ col,
                                               const float* __restrict__ dinv,
                                               const float* __restrict__ h,
                                               const float* __restrict__ h0,
                                               float* __restrict__ out) {
    int node = blockIdx.x * 8 + (threadIdx.x >> 5);
    if (node >= NN) return;
    int c = threadIdx.x & 31;
    int beg = row_ptr[node];
    int end = row_ptr[node + 1];
    float dd = dinv[node];
    float t = dd * h[(size_t)node * 32 + c];
    for (int e = beg; e < end; e++) {
        int s = col[e];
        t = fmaf(dinv[s], h[(size_t)s * 32 + c], t);
    }
    float agg = dd * t;
    out[(size_t)node * 32 + c] = 0.9f * agg + 0.1f * h0[(size_t)node * 32 + c];
}

// ---------------- launch ----------------

extern "C" void kernel_launch(void* const* d_in, const int* in_sizes, int n_in,
                              void* d_out, int out_size, void* d_ws, size_t ws_size,
                              hipStream_t stream) {
    const float* x     = (const float*)d_in[0];
    const int*   ei    = (const int*)d_in[1];
    const float* W_in  = (const float*)d_in[2];
    const float* b_in  = (const float*)d_in[3];
    const float* W_h   = (const float*)d_in[4];
    const float* b_h   = (const float*)d_in[5];
    const float* W_out = (const float*)d_in[6];
    const float* b_out = (const float*)d_in[7];
    float* out = (float*)d_out;

    const int* srcv = ei;
    const int* dstv = ei + NE;

    char* ws = (char*)d_ws;
    _Float16* h1h  = (_Float16*)ws;                              // M_PAD*256 f16
    _Float16* h2h  = h1h + (size_t)M_PAD * 256;                  // M_PAD*256 f16
    float* h0      = (float*)(h2h + (size_t)M_PAD * 256);        // NN*32 f32
    float* hb      = h0 + (size_t)NN * 32;                       // NN*32
    float* dinv    = hb + (size_t)NN * 32;                       // NN
    _Float16* Wf_in  = (_Float16*)(dinv + NN);                   // 256*256
    _Float16* Wf_h   = Wf_in + 256 * 256;                        // 256*256
    _Float16* Wf_out = Wf_h + 256 * 256;                         // 256*32
    int* cnt     = (int*)(Wf_out + 256 * 32);                    // NN
    int* part    = cnt + NN;                                     // NN
    int* row_ptr = part + NN;                                    // NN+1
    int* cursor  = row_ptr + NN + 1;                             // NN
    int* bsum    = cursor + NN;                                  // <=512
    int* col     = bsum + 512;                                   // NE

    const int NB = (NN + 255) / 256;
    const int EB = (NE + 255) / 256;
    const int GB = M_PAD / 64;  // 1563 gemm blocks

    // --- CSR build + dinv ---
    k_zero_int<<<NB, 256, 0, stream>>>(cnt, NN);
    k_hist<<<EB, 256, 0, stream>>>(dstv, cnt);
    k_scan1<<<NB, 256, 0, stream>>>(cnt, part, bsum, NN);
    k_scan2<<<1, 512, 0, stream>>>(bsum, NB);
    k_scan3<<<NB, 256, 0, stream>>>(part, bsum, cnt, row_ptr, cursor, dinv, NN);
    k_reorder<<<EB, 256, 0, stream>>>(srcv, dstv, cursor, col);

    // --- W fragment conversion ---
    k_wfrag<256><<<(256 * 256 + 255) / 256, 256, 0, stream>>>(W_in, Wf_in);
    k_wfrag<256><<<(256 * 256 + 255) / 256, 256, 0, stream>>>(W_h, Wf_h);
    k_wfrag<32 ><<<(256 * 32 + 255) / 256, 256, 0, stream>>>(W_out, Wf_out);

    // --- MLP (fp16 MFMA) ---
    k_gemm_mfma<256, true,  true,  true ><<<GB, 256, 0, stream>>>(x,   Wf_in,  b_in,  h1h);
    k_gemm_mfma<256, true,  false, true ><<<GB, 256, 0, stream>>>(h1h, Wf_h,   b_h,   h2h);
    k_gemm_mfma<32,  false, false, false><<<GB, 256, 0, stream>>>(h2h, Wf_out, b_out, h0);

    // --- APPNP: K = 2 ---
    k_appnp<<<(NN + 7) / 8, 256, 0, stream>>>(row_ptr, col, dinv, h0, h0, hb);
    k_appnp<<<(NN + 7) / 8, 256, 0, stream>>>(row_ptr, col, dinv, hb, h0, out);
}